// Round 2
// baseline (6269.122 us; speedup 1.0000x reference)
//
#include <hip/hip_runtime.h>
#include <math.h>

#define HD   2048
#define NH_  16
#define DH_  128
#define SEQ_ 2048
#define B_   4
#define NT_  (B_*SEQ_)
#define EPS_ 1e-5f

// ---------------- block-wide sum over 256 threads (4 waves) ----------------
__device__ __forceinline__ float block_sum256(float v, float* red) {
#pragma unroll
  for (int o = 32; o > 0; o >>= 1) v += __shfl_down(v, o);
  int lane = threadIdx.x & 63, wid = threadIdx.x >> 6;
  __syncthreads();
  if (lane == 0) red[wid] = v;
  __syncthreads();
  return red[0] + red[1] + red[2] + red[3];
}

// ---------------- workspace diagnostic (ws too small) ----------------------
__global__ void ws_diag_kernel(float* out, float v) { out[0] = v; }

// ---------------- RoPE cos/sin table (fp64 for accuracy) -------------------
__global__ void rope_table_kernel(float* __restrict__ ct, float* __restrict__ st) {
  int i = blockIdx.x * 256 + threadIdx.x;
  if (i >= SEQ_ * 64) return;
  int l = i >> 6, d = i & 63;
  // inv_freq = 10000^(-d/64); log2(10000) = 13.287712379549449
  double invf = exp2(-(double)d * (13.287712379549449 / 64.0));
  double ang = (double)l * invf;
  ct[i] = (float)cos(ang);
  st[i] = (float)sin(ang);
}

// ---------------- LN1 row stats: mu, rsqrt(var+eps) ------------------------
__global__ __launch_bounds__(256) void ln_stats_kernel(const float* __restrict__ x,
    float* __restrict__ mu_out, float* __restrict__ rs_out) {
  __shared__ float red[4];
  int t = threadIdx.x;
  const float4* xr = (const float4*)(x + (size_t)blockIdx.x * HD);
  float4 a = xr[t], b = xr[t + 256];
  float s = a.x + a.y + a.z + a.w + b.x + b.y + b.z + b.w;
  s = block_sum256(s, red);
  float mu = s * (1.0f / HD);
  float dx[8] = {a.x - mu, a.y - mu, a.z - mu, a.w - mu,
                 b.x - mu, b.y - mu, b.z - mu, b.w - mu};
  float ss = 0.f;
#pragma unroll
  for (int i = 0; i < 8; ++i) ss += dx[i] * dx[i];
  ss = block_sum256(ss, red);
  if (t == 0) {
    mu_out[blockIdx.x] = mu;
    rs_out[blockIdx.x] = rsqrtf(ss * (1.0f / HD) + EPS_);
  }
}

// ---------------- RoPE application helper (4 consecutive dims) -------------
__device__ __forceinline__ float4 rope4(const float* buf, int g, int pos,
                                        const float* __restrict__ ct,
                                        const float* __restrict__ st) {
  int d = g & 127;
  float4 o;
  if (d < 64) {
    float4 c  = *(const float4*)&ct[pos * 64 + d];
    float4 sn = *(const float4*)&st[pos * 64 + d];
    o.x = buf[g+0]*c.x - buf[g+64]*sn.x;
    o.y = buf[g+1]*c.y - buf[g+65]*sn.y;
    o.z = buf[g+2]*c.z - buf[g+66]*sn.z;
    o.w = buf[g+3]*c.w - buf[g+67]*sn.w;
  } else {
    int d2 = d - 64;
    float4 c  = *(const float4*)&ct[pos * 64 + d2];
    float4 sn = *(const float4*)&st[pos * 64 + d2];
    o.x = buf[g+0]*c.x + buf[g-64]*sn.x;
    o.y = buf[g+1]*c.y + buf[g-63]*sn.y;
    o.z = buf[g+2]*c.z + buf[g-62]*sn.z;
    o.w = buf[g+3]*c.w + buf[g-61]*sn.w;
  }
  return o;
}

// ---------------- fused Q/K layernorm (no bias) + RoPE, in place -----------
__global__ __launch_bounds__(256) void qkln_rope_kernel(float* __restrict__ qkv,
    const float* __restrict__ qw, const float* __restrict__ kw,
    const float* __restrict__ ct, const float* __restrict__ st) {
  __shared__ float red[4];
  __shared__ float buf[HD];
  int t = threadIdx.x;
  int tok = blockIdx.x;
  int pos = tok & (SEQ_ - 1);
  for (int part = 0; part < 2; ++part) {
    float* base = qkv + (size_t)tok * (3 * HD) + (size_t)part * HD;
    const float* w = part ? kw : qw;
    float4 a = ((const float4*)base)[t];
    float4 b = ((const float4*)base)[t + 256];
    float s = a.x + a.y + a.z + a.w + b.x + b.y + b.z + b.w;
    s = block_sum256(s, red);
    float mu = s * (1.0f / HD);
    float dx[8] = {a.x - mu, a.y - mu, a.z - mu, a.w - mu,
                   b.x - mu, b.y - mu, b.z - mu, b.w - mu};
    float ss = 0.f;
#pragma unroll
    for (int i = 0; i < 8; ++i) ss += dx[i] * dx[i];
    ss = block_sum256(ss, red);
    float rs = rsqrtf(ss * (1.0f / HD) + EPS_);
    float4 w0 = ((const float4*)w)[t], w1 = ((const float4*)w)[t + 256];
    int i0 = t * 4, i1 = 1024 + t * 4;
    buf[i0+0] = dx[0]*rs*w0.x; buf[i0+1] = dx[1]*rs*w0.y;
    buf[i0+2] = dx[2]*rs*w0.z; buf[i0+3] = dx[3]*rs*w0.w;
    buf[i1+0] = dx[4]*rs*w1.x; buf[i1+1] = dx[5]*rs*w1.y;
    buf[i1+2] = dx[6]*rs*w1.z; buf[i1+3] = dx[7]*rs*w1.w;
    __syncthreads();
    float4 o0 = rope4(buf, i0, pos, ct, st);
    float4 o1 = rope4(buf, i1, pos, ct, st);
    ((float4*)base)[t] = o0;
    ((float4*)base)[t + 256] = o1;
    __syncthreads();
  }
}

// ---------------- fp32 tiled GEMM: C = lnA[MxK] * W[KxN] + bias ------------
// BM=BN=128, BK=16, 256 threads, 8x8 microtile (split 4+4 to dodge conflicts)
// FUSE: A-elements get (x-mu)*rs*lnw[k] + lnb[k] applied while staging.
template<bool FUSE>
__global__ __launch_bounds__(256) void gemm_f32_kernel(
    const float* __restrict__ A, int lda,
    const float* __restrict__ mu, const float* __restrict__ rs,
    const float* __restrict__ lnw, const float* __restrict__ lnb,
    const float* __restrict__ W, const float* __restrict__ bias,
    float* __restrict__ C, int M, int N, int K) {
  __shared__ float As[16][132];
  __shared__ float Bs[16][132];
  int row0 = blockIdx.y << 7, col0 = blockIdx.x << 7;
  int t = threadIdx.x, tx = t & 15, ty = t >> 4;
  int arow = t >> 2, akc = (t & 3) << 2;   // A tile: 128 rows x 16 k
  int brow = t >> 5, bc = (t & 31) << 2;   // B tile: 16 k x 128 cols
  const float* Ap0 = A + (size_t)(row0 + arow) * lda + akc;
  const float* Ap1 = A + (size_t)(row0 + arow + 64) * lda + akc;
  const float* Wp0 = W + (size_t)brow * N + col0 + bc;
  const float* Wp1 = W + (size_t)(brow + 8) * N + col0 + bc;
  float mu0 = 0.f, rs0 = 1.f, mu1 = 0.f, rs1 = 1.f;
  if (FUSE) {
    mu0 = mu[row0 + arow];      rs0 = rs[row0 + arow];
    mu1 = mu[row0 + arow + 64]; rs1 = rs[row0 + arow + 64];
  }
  float acc[8][8] = {};
  for (int k0 = 0; k0 < K; k0 += 16) {
    float4 a0 = *(const float4*)(Ap0 + k0);
    float4 a1 = *(const float4*)(Ap1 + k0);
    float4 b0 = *(const float4*)(Wp0 + (size_t)k0 * N);
    float4 b1 = *(const float4*)(Wp1 + (size_t)k0 * N);
    if (FUSE) {
      float4 w4 = *(const float4*)(lnw + k0 + akc);
      float4 b4 = *(const float4*)(lnb + k0 + akc);
      a0.x = (a0.x - mu0) * rs0 * w4.x + b4.x;
      a0.y = (a0.y - mu0) * rs0 * w4.y + b4.y;
      a0.z = (a0.z - mu0) * rs0 * w4.z + b4.z;
      a0.w = (a0.w - mu0) * rs0 * w4.w + b4.w;
      a1.x = (a1.x - mu1) * rs1 * w4.x + b4.x;
      a1.y = (a1.y - mu1) * rs1 * w4.y + b4.y;
      a1.z = (a1.z - mu1) * rs1 * w4.z + b4.z;
      a1.w = (a1.w - mu1) * rs1 * w4.w + b4.w;
    }
    __syncthreads();
    As[akc+0][arow] = a0.x; As[akc+1][arow] = a0.y;
    As[akc+2][arow] = a0.z; As[akc+3][arow] = a0.w;
    As[akc+0][arow+64] = a1.x; As[akc+1][arow+64] = a1.y;
    As[akc+2][arow+64] = a1.z; As[akc+3][arow+64] = a1.w;
    *(float4*)&Bs[brow][bc]   = b0;
    *(float4*)&Bs[brow+8][bc] = b1;
    __syncthreads();
#pragma unroll
    for (int k = 0; k < 16; ++k) {
      float av[8], bv[8];
      *(float4*)&av[0] = *(const float4*)&As[k][ty << 2];
      *(float4*)&av[4] = *(const float4*)&As[k][64 + (ty << 2)];
      *(float4*)&bv[0] = *(const float4*)&Bs[k][tx << 2];
      *(float4*)&bv[4] = *(const float4*)&Bs[k][64 + (tx << 2)];
#pragma unroll
      for (int i = 0; i < 8; ++i)
#pragma unroll
        for (int j = 0; j < 8; ++j)
          acc[i][j] = fmaf(av[i], bv[j], acc[i][j]);
    }
  }
#pragma unroll
  for (int i = 0; i < 8; ++i) {
    int r = row0 + ((i < 4) ? (ty * 4 + i) : (64 + ty * 4 + i - 4));
    float* Cr = C + (size_t)r * N + col0;
    int c0 = tx * 4, c1 = 64 + tx * 4;
    float4 o;
    o.x = acc[i][0] + bias[col0+c0+0]; o.y = acc[i][1] + bias[col0+c0+1];
    o.z = acc[i][2] + bias[col0+c0+2]; o.w = acc[i][3] + bias[col0+c0+3];
    *(float4*)&Cr[c0] = o;
    o.x = acc[i][4] + bias[col0+c1+0]; o.y = acc[i][5] + bias[col0+c1+1];
    o.z = acc[i][6] + bias[col0+c1+2]; o.w = acc[i][7] + bias[col0+c1+3];
    *(float4*)&Cr[c1] = o;
  }
}

// ---------------- flash attention, fp32, 64 q-rows per block ---------------
// grid (SEQ/64, B*NH), 256 threads. Online softmax fully in registers
// (row stats replicated across the 16 tx lanes of each row group).
// Output is written IN PLACE over the Q slice this block loaded (safe:
// no other block reads those (token, head) Q elements).
__global__ __launch_bounds__(256) void attn_kernel(float* __restrict__ qkv) {
  __shared__ float Qs[64][DH_ + 4];
  __shared__ float KsT[DH_][68];
  __shared__ float Vs[64][DH_ + 4];
  __shared__ float Ps[64][68];
  int bh = blockIdx.y;
  int b = bh >> 4, h = bh & 15;
  int q0 = blockIdx.x << 6;
  int t = threadIdx.x, tx = t & 15, ty = t >> 4;
  const size_t rstride = 3 * HD;
  float* Qg = qkv + (size_t)b * SEQ_ * rstride + h * DH_;
  const float* Kg = Qg + HD;
  const float* Vg = Qg + 2 * HD;
  const float scale = 0.08838834764831845f;  // 1/sqrt(128)
  int lr = t >> 5;
  int lc = (t & 31) << 2;
#pragma unroll
  for (int i = 0; i < 8; ++i) {
    int r = lr + i * 8;
    float4 v = *(const float4*)&Qg[(size_t)(q0 + r) * rstride + lc];
    Qs[r][lc+0] = v.x * scale; Qs[r][lc+1] = v.y * scale;
    Qs[r][lc+2] = v.z * scale; Qs[r][lc+3] = v.w * scale;
  }
  float Oa[4][8] = {};
  float mrow[4] = {-1e30f, -1e30f, -1e30f, -1e30f};
  float lrow[4] = {0.f, 0.f, 0.f, 0.f};
  for (int kt = 0; kt < SEQ_; kt += 64) {
    float4 kr[8], vr[8];
#pragma unroll
    for (int i = 0; i < 8; ++i) {
      int r = lr + i * 8;
      kr[i] = *(const float4*)&Kg[(size_t)(kt + r) * rstride + lc];
      vr[i] = *(const float4*)&Vg[(size_t)(kt + r) * rstride + lc];
    }
    __syncthreads();  // previous tile's S/PV reads done before overwrite
#pragma unroll
    for (int i = 0; i < 8; ++i) {
      int r = lr + i * 8;
      KsT[lc+0][r] = kr[i].x; KsT[lc+1][r] = kr[i].y;
      KsT[lc+2][r] = kr[i].z; KsT[lc+3][r] = kr[i].w;
      *(float4*)&Vs[r][lc] = vr[i];
    }
    __syncthreads();
    // ---- S = Q K^T (64x64), thread -> 4x4 ----
    float sac[4][4] = {};
    for (int k = 0; k < DH_; k += 4) {
      float qa[4][4], kb[4][4];
#pragma unroll
      for (int i = 0; i < 4; ++i)
        *(float4*)qa[i] = *(const float4*)&Qs[ty * 4 + i][k];
#pragma unroll
      for (int kk = 0; kk < 4; ++kk)
        *(float4*)kb[kk] = *(const float4*)&KsT[k + kk][tx * 4];
#pragma unroll
      for (int i = 0; i < 4; ++i)
#pragma unroll
        for (int kk = 0; kk < 4; ++kk)
#pragma unroll
          for (int j = 0; j < 4; ++j)
            sac[i][j] = fmaf(qa[i][kk], kb[kk][j], sac[i][j]);
    }
    // ---- online softmax, register + shfl (rows shared by 16 tx lanes) ----
    float fs[4];
#pragma unroll
    for (int i = 0; i < 4; ++i) {
      float mx = fmaxf(fmaxf(sac[i][0], sac[i][1]), fmaxf(sac[i][2], sac[i][3]));
#pragma unroll
      for (int off = 1; off < 16; off <<= 1) mx = fmaxf(mx, __shfl_xor(mx, off));
      float mn = fmaxf(mrow[i], mx);
      fs[i] = __expf(mrow[i] - mn);
      mrow[i] = mn;
      float psum = 0.f;
#pragma unroll
      for (int j = 0; j < 4; ++j) {
        float p = __expf(sac[i][j] - mn);
        sac[i][j] = p;
        psum += p;
      }
#pragma unroll
      for (int off = 1; off < 16; off <<= 1) psum += __shfl_xor(psum, off);
      lrow[i] = lrow[i] * fs[i] + psum;
    }
#pragma unroll
    for (int i = 0; i < 4; ++i)
      *(float4*)&Ps[ty * 4 + i][tx * 4] = *(float4*)sac[i];
#pragma unroll
    for (int i = 0; i < 4; ++i)
#pragma unroll
      for (int j = 0; j < 8; ++j) Oa[i][j] *= fs[i];
    __syncthreads();
    // ---- O += P V (64 keys x 128 dims), thread -> 4 rows x (4+4) cols ----
    for (int c = 0; c < 64; c += 4) {
      float pa[4][4], vb[4][8];
#pragma unroll
      for (int i = 0; i < 4; ++i)
        *(float4*)pa[i] = *(const float4*)&Ps[ty * 4 + i][c];
#pragma unroll
      for (int cc = 0; cc < 4; ++cc) {
        *(float4*)&vb[cc][0] = *(const float4*)&Vs[c + cc][tx * 4];
        *(float4*)&vb[cc][4] = *(const float4*)&Vs[c + cc][64 + tx * 4];
      }
#pragma unroll
      for (int i = 0; i < 4; ++i)
#pragma unroll
        for (int cc = 0; cc < 4; ++cc)
#pragma unroll
          for (int j = 0; j < 8; ++j)
            Oa[i][j] = fmaf(pa[i][cc], vb[cc][j], Oa[i][j]);
    }
  }
  float invl[4];
#pragma unroll
  for (int i = 0; i < 4; ++i) invl[i] = 1.0f / lrow[i];
#pragma unroll
  for (int i = 0; i < 4; ++i) {
    float* orow = Qg + (size_t)(q0 + ty * 4 + i) * rstride;  // in-place over Q
    float4 o;
    o.x = Oa[i][0] * invl[i]; o.y = Oa[i][1] * invl[i];
    o.z = Oa[i][2] * invl[i]; o.w = Oa[i][3] * invl[i];
    *(float4*)&orow[tx * 4] = o;
    o.x = Oa[i][4] * invl[i]; o.y = Oa[i][5] * invl[i];
    o.z = Oa[i][6] * invl[i]; o.w = Oa[i][7] * invl[i];
    *(float4*)&orow[64 + tx * 4] = o;
  }
}

// ---------------------------------------------------------------------------
extern "C" void kernel_launch(void* const* d_in, const int* in_sizes, int n_in,
                              void* d_out, int out_size, void* d_ws, size_t ws_size,
                              hipStream_t stream) {
  const float* x    = (const float*)d_in[0];
  const float* ln1w = (const float*)d_in[1];
  const float* ln1b = (const float*)d_in[2];
  const float* Wqkv = (const float*)d_in[3];
  const float* bqkv = (const float*)d_in[4];
  const float* qlnw = (const float*)d_in[5];
  const float* klnw = (const float*)d_in[6];
  const float* Wo   = (const float*)d_in[7];
  const float* bo   = (const float*)d_in[8];
  float* out = (float*)d_out;
  float* ws  = (float*)d_ws;

  // workspace layout (floats): qkv [NT*3H] | mu [NT] | rs [NT] | cos | sin
  const size_t qkv_f  = (size_t)NT_ * 3 * HD;          // 50,331,648
  const size_t need_f = qkv_f + 2 * NT_ + 2 * SEQ_ * 64;
  const size_t need_bytes = need_f * 4;                 // ~193.1 MiB
  if (ws_size < need_bytes) {
    // Diagnostic: surface the actual workspace budget (in MB) as the absmax.
    ws_diag_kernel<<<1, 1, 0, stream>>>(out, (float)(ws_size >> 20));
    return;
  }
  float* qkv  = ws;
  float* muv  = qkv + qkv_f;
  float* rsv  = muv + NT_;
  float* ctab = rsv + NT_;
  float* stab = ctab + (size_t)SEQ_ * 64;

  rope_table_kernel<<<(SEQ_ * 64 + 255) / 256, 256, 0, stream>>>(ctab, stab);
  ln_stats_kernel<<<NT_, 256, 0, stream>>>(x, muv, rsv);
  gemm_f32_kernel<true><<<dim3(3 * HD / 128, NT_ / 128), 256, 0, stream>>>(
      x, HD, muv, rsv, ln1w, ln1b, Wqkv, bqkv, qkv, NT_, 3 * HD, HD);
  qkln_rope_kernel<<<NT_, 256, 0, stream>>>(qkv, qlnw, klnw, ctab, stab);
  attn_kernel<<<dim3(SEQ_ / 64, B_ * NH_), 256, 0, stream>>>(qkv);
  gemm_f32_kernel<false><<<dim3(HD / 128, NT_ / 128), 256, 0, stream>>>(
      qkv, 3 * HD, nullptr, nullptr, nullptr, nullptr, Wo, bo, out,
      NT_, HD, HD);
}

// Round 3
// 3508.976 us; speedup vs baseline: 1.7866x; 1.7866x over previous
//
#include <hip/hip_runtime.h>
#include <math.h>

#define HD   2048
#define NH_  16
#define DH_  128
#define SEQ_ 2048
#define B_   4
#define NT_  (B_*SEQ_)
#define EPS_ 1e-5f

typedef __attribute__((ext_vector_type(8))) __bf16 bf16x8;
typedef __attribute__((ext_vector_type(4))) __bf16 bf16x4;
typedef __attribute__((ext_vector_type(4))) float f32x4;

// ---------------- block-wide sum over 256 threads (4 waves) ----------------
__device__ __forceinline__ float block_sum256(float v, float* red) {
#pragma unroll
  for (int o = 32; o > 0; o >>= 1) v += __shfl_down(v, o);
  int lane = threadIdx.x & 63, wid = threadIdx.x >> 6;
  __syncthreads();
  if (lane == 0) red[wid] = v;
  __syncthreads();
  return red[0] + red[1] + red[2] + red[3];
}

// ---------------- workspace diagnostic (ws too small) ----------------------
__global__ void ws_diag_kernel(float* out, float v) { out[0] = v; }

// ---------------- RoPE cos/sin table (fp64 for accuracy) -------------------
__global__ void rope_table_kernel(float* __restrict__ ct, float* __restrict__ st) {
  int i = blockIdx.x * 256 + threadIdx.x;
  if (i >= SEQ_ * 64) return;
  int l = i >> 6, d = i & 63;
  double invf = exp2(-(double)d * (13.287712379549449 / 64.0));
  double ang = (double)l * invf;
  ct[i] = (float)cos(ang);
  st[i] = (float)sin(ang);
}

// ---------------- LN1 row stats: mu, rsqrt(var+eps) ------------------------
__global__ __launch_bounds__(256) void ln_stats_kernel(const float* __restrict__ x,
    float* __restrict__ mu_out, float* __restrict__ rs_out) {
  __shared__ float red[4];
  int t = threadIdx.x;
  const float4* xr = (const float4*)(x + (size_t)blockIdx.x * HD);
  float4 a = xr[t], b = xr[t + 256];
  float s = a.x + a.y + a.z + a.w + b.x + b.y + b.z + b.w;
  s = block_sum256(s, red);
  float mu = s * (1.0f / HD);
  float dx[8] = {a.x - mu, a.y - mu, a.z - mu, a.w - mu,
                 b.x - mu, b.y - mu, b.z - mu, b.w - mu};
  float ss = 0.f;
#pragma unroll
  for (int i = 0; i < 8; ++i) ss += dx[i] * dx[i];
  ss = block_sum256(ss, red);
  if (t == 0) {
    mu_out[blockIdx.x] = mu;
    rs_out[blockIdx.x] = rsqrtf(ss * (1.0f / HD) + EPS_);
  }
}

// ---------------- RoPE application helper (4 consecutive dims) -------------
__device__ __forceinline__ float4 rope4(const float* buf, int g, int pos,
                                        const float* __restrict__ ct,
                                        const float* __restrict__ st) {
  int d = g & 127;
  float4 o;
  if (d < 64) {
    float4 cc  = *(const float4*)&ct[pos * 64 + d];
    float4 sn = *(const float4*)&st[pos * 64 + d];
    o.x = buf[g+0]*cc.x - buf[g+64]*sn.x;
    o.y = buf[g+1]*cc.y - buf[g+65]*sn.y;
    o.z = buf[g+2]*cc.z - buf[g+66]*sn.z;
    o.w = buf[g+3]*cc.w - buf[g+67]*sn.w;
  } else {
    int d2 = d - 64;
    float4 cc  = *(const float4*)&ct[pos * 64 + d2];
    float4 sn = *(const float4*)&st[pos * 64 + d2];
    o.x = buf[g+0]*cc.x + buf[g-64]*sn.x;
    o.y = buf[g+1]*cc.y + buf[g-63]*sn.y;
    o.z = buf[g+2]*cc.z + buf[g-62]*sn.z;
    o.w = buf[g+3]*cc.w + buf[g-61]*sn.w;
  }
  return o;
}

// ---------------- fused Q/K layernorm (no bias) + RoPE, in place -----------
__global__ __launch_bounds__(256) void qkln_rope_kernel(float* __restrict__ qkv,
    const float* __restrict__ qw, const float* __restrict__ kw,
    const float* __restrict__ ct, const float* __restrict__ st) {
  __shared__ float red[4];
  __shared__ float buf[HD];
  int t = threadIdx.x;
  int tok = blockIdx.x;
  int pos = tok & (SEQ_ - 1);
  for (int part = 0; part < 2; ++part) {
    float* base = qkv + (size_t)tok * (3 * HD) + (size_t)part * HD;
    const float* w = part ? kw : qw;
    float4 a = ((const float4*)base)[t];
    float4 b = ((const float4*)base)[t + 256];
    float s = a.x + a.y + a.z + a.w + b.x + b.y + b.z + b.w;
    s = block_sum256(s, red);
    float mu = s * (1.0f / HD);
    float dx[8] = {a.x - mu, a.y - mu, a.z - mu, a.w - mu,
                   b.x - mu, b.y - mu, b.z - mu, b.w - mu};
    float ss = 0.f;
#pragma unroll
    for (int i = 0; i < 8; ++i) ss += dx[i] * dx[i];
    ss = block_sum256(ss, red);
    float rs = rsqrtf(ss * (1.0f / HD) + EPS_);
    float4 w0 = ((const float4*)w)[t], w1 = ((const float4*)w)[t + 256];
    int i0 = t * 4, i1 = 1024 + t * 4;
    buf[i0+0] = dx[0]*rs*w0.x; buf[i0+1] = dx[1]*rs*w0.y;
    buf[i0+2] = dx[2]*rs*w0.z; buf[i0+3] = dx[3]*rs*w0.w;
    buf[i1+0] = dx[4]*rs*w1.x; buf[i1+1] = dx[5]*rs*w1.y;
    buf[i1+2] = dx[6]*rs*w1.z; buf[i1+3] = dx[7]*rs*w1.w;
    __syncthreads();
    float4 o0 = rope4(buf, i0, pos, ct, st);
    float4 o1 = rope4(buf, i1, pos, ct, st);
    ((float4*)base)[t] = o0;
    ((float4*)base)[t + 256] = o1;
    __syncthreads();
  }
}

// ---------------- fp32 tiled GEMM: C = lnA[MxK] * W[KxN] + bias ------------
template<bool FUSE>
__global__ __launch_bounds__(256) void gemm_f32_kernel(
    const float* __restrict__ A, int lda,
    const float* __restrict__ mu, const float* __restrict__ rs,
    const float* __restrict__ lnw, const float* __restrict__ lnb,
    const float* __restrict__ W, const float* __restrict__ bias,
    float* __restrict__ C, int M, int N, int K) {
  __shared__ float As[16][132];
  __shared__ float Bs[16][132];
  int row0 = blockIdx.y << 7, col0 = blockIdx.x << 7;
  int t = threadIdx.x, tx = t & 15, ty = t >> 4;
  int arow = t >> 2, akc = (t & 3) << 2;
  int brow = t >> 5, bc = (t & 31) << 2;
  const float* Ap0 = A + (size_t)(row0 + arow) * lda + akc;
  const float* Ap1 = A + (size_t)(row0 + arow + 64) * lda + akc;
  const float* Wp0 = W + (size_t)brow * N + col0 + bc;
  const float* Wp1 = W + (size_t)(brow + 8) * N + col0 + bc;
  float mu0 = 0.f, rs0 = 1.f, mu1 = 0.f, rs1 = 1.f;
  if (FUSE) {
    mu0 = mu[row0 + arow];      rs0 = rs[row0 + arow];
    mu1 = mu[row0 + arow + 64]; rs1 = rs[row0 + arow + 64];
  }
  float acc[8][8] = {};
  for (int k0 = 0; k0 < K; k0 += 16) {
    float4 a0 = *(const float4*)(Ap0 + k0);
    float4 a1 = *(const float4*)(Ap1 + k0);
    float4 b0 = *(const float4*)(Wp0 + (size_t)k0 * N);
    float4 b1 = *(const float4*)(Wp1 + (size_t)k0 * N);
    if (FUSE) {
      float4 w4 = *(const float4*)(lnw + k0 + akc);
      float4 b4 = *(const float4*)(lnb + k0 + akc);
      a0.x = (a0.x - mu0) * rs0 * w4.x + b4.x;
      a0.y = (a0.y - mu0) * rs0 * w4.y + b4.y;
      a0.z = (a0.z - mu0) * rs0 * w4.z + b4.z;
      a0.w = (a0.w - mu0) * rs0 * w4.w + b4.w;
      a1.x = (a1.x - mu1) * rs1 * w4.x + b4.x;
      a1.y = (a1.y - mu1) * rs1 * w4.y + b4.y;
      a1.z = (a1.z - mu1) * rs1 * w4.z + b4.z;
      a1.w = (a1.w - mu1) * rs1 * w4.w + b4.w;
    }
    __syncthreads();
    As[akc+0][arow] = a0.x; As[akc+1][arow] = a0.y;
    As[akc+2][arow] = a0.z; As[akc+3][arow] = a0.w;
    As[akc+0][arow+64] = a1.x; As[akc+1][arow+64] = a1.y;
    As[akc+2][arow+64] = a1.z; As[akc+3][arow+64] = a1.w;
    *(float4*)&Bs[brow][bc]   = b0;
    *(float4*)&Bs[brow+8][bc] = b1;
    __syncthreads();
#pragma unroll
    for (int k = 0; k < 16; ++k) {
      float av[8], bv[8];
      *(float4*)&av[0] = *(const float4*)&As[k][ty << 2];
      *(float4*)&av[4] = *(const float4*)&As[k][64 + (ty << 2)];
      *(float4*)&bv[0] = *(const float4*)&Bs[k][tx << 2];
      *(float4*)&bv[4] = *(const float4*)&Bs[k][64 + (tx << 2)];
#pragma unroll
      for (int i = 0; i < 8; ++i)
#pragma unroll
        for (int j = 0; j < 8; ++j)
          acc[i][j] = fmaf(av[i], bv[j], acc[i][j]);
    }
  }
#pragma unroll
  for (int i = 0; i < 8; ++i) {
    int r = row0 + ((i < 4) ? (ty * 4 + i) : (64 + ty * 4 + i - 4));
    float* Cr = C + (size_t)r * N + col0;
    int c0 = tx * 4, c1 = 64 + tx * 4;
    float4 o;
    o.x = acc[i][0] + bias[col0+c0+0]; o.y = acc[i][1] + bias[col0+c0+1];
    o.z = acc[i][2] + bias[col0+c0+2]; o.w = acc[i][3] + bias[col0+c0+3];
    *(float4*)&Cr[c0] = o;
    o.x = acc[i][4] + bias[col0+c1+0]; o.y = acc[i][5] + bias[col0+c1+1];
    o.z = acc[i][6] + bias[col0+c1+2]; o.w = acc[i][7] + bias[col0+c1+3];
    *(float4*)&Cr[c1] = o;
  }
}

// ---------------- flash attention, bf16 MFMA, 128 q-rows per block ---------
// 4 waves x 32 q-rows. mfma_f32_16x16x32_bf16.
// A-frag: row=lane&15, k=(lane>>4)*8+j ; B-frag: col=lane&15, same k
// D-frag: col=lane&15, row=(lane>>4)*4+reg   (guide §3, m89-verified)
// K in LDS row-major [64][136] bf16; V transposed [128][72]; P [128][72].
// Output written in place over the Q slice this block consumed.
__global__ __launch_bounds__(256, 2) void attn_mfma_kernel(float* __restrict__ qkv) {
  __shared__ __bf16 Kb[64][136];
  __shared__ __bf16 Vt[128][72];
  __shared__ __bf16 Pl[128][72];
  const int bh = blockIdx.y, b = bh >> 4, h = bh & 15;
  const int q0 = blockIdx.x << 7;
  const int t = threadIdx.x;
  const int lane = t & 63, wave = t >> 6, g = lane >> 4, c = lane & 15;
  const int wq = wave * 32;
  const size_t rstr = 3 * HD;
  float* Qg = qkv + (size_t)b * SEQ_ * rstr + (size_t)h * DH_;
  const float* Kg = Qg + HD;
  const float* Vg = Qg + 2 * HD;
  const float scale = 0.08838834764831845f;  // 1/sqrt(128)

  // ---- Q A-frags (bf16, pre-scaled) held in registers for whole kernel ----
  bf16x8 qf[2][4];
#pragma unroll
  for (int rt = 0; rt < 2; ++rt) {
    const float* qr = Qg + (size_t)(q0 + wq + rt * 16 + c) * rstr;
#pragma unroll
    for (int kc = 0; kc < 4; ++kc) {
      const int d0 = kc * 32 + g * 8;
      float4 x0 = *(const float4*)(qr + d0);
      float4 x1 = *(const float4*)(qr + d0 + 4);
      bf16x8 f;
      f[0] = (__bf16)(x0.x * scale); f[1] = (__bf16)(x0.y * scale);
      f[2] = (__bf16)(x0.z * scale); f[3] = (__bf16)(x0.w * scale);
      f[4] = (__bf16)(x1.x * scale); f[5] = (__bf16)(x1.y * scale);
      f[6] = (__bf16)(x1.z * scale); f[7] = (__bf16)(x1.w * scale);
      qf[rt][kc] = f;
    }
  }

  f32x4 Oa[2][8];
#pragma unroll
  for (int rt = 0; rt < 2; ++rt)
#pragma unroll
    for (int dt = 0; dt < 8; ++dt) Oa[rt][dt] = f32x4{0.f, 0.f, 0.f, 0.f};
  float m_[2][4], l_[2][4];
#pragma unroll
  for (int rt = 0; rt < 2; ++rt)
#pragma unroll
    for (int r = 0; r < 4; ++r) { m_[rt][r] = -1e30f; l_[rt][r] = 0.f; }

  const int kkey = t >> 5;          // K-stage: 0..7, +8i
  const int kd   = (t & 31) * 4;    // K-stage dims
  const int vkey = t & 63;          // V-stage: key-major lanes (LDS-write friendly)
  const int vd0  = (t >> 6) * 32;   // V-stage: wave's dim chunk

  for (int kt = 0; kt < SEQ_; kt += 64) {
    // ---- load K,V tile to registers (fp32) ----
    float4 kv[8], vv[8];
#pragma unroll
    for (int i = 0; i < 8; ++i)
      kv[i] = *(const float4*)(Kg + (size_t)(kt + kkey + i * 8) * rstr + kd);
#pragma unroll
    for (int i = 0; i < 8; ++i)
      vv[i] = *(const float4*)(Vg + (size_t)(kt + vkey) * rstr + vd0 + i * 4);
    __syncthreads();   // previous tile's LDS reads complete
    // ---- stage to LDS as bf16 ----
#pragma unroll
    for (int i = 0; i < 8; ++i) {
      bf16x4 kk;
      kk[0] = (__bf16)kv[i].x; kk[1] = (__bf16)kv[i].y;
      kk[2] = (__bf16)kv[i].z; kk[3] = (__bf16)kv[i].w;
      *(bf16x4*)&Kb[kkey + i * 8][kd] = kk;
      const int d = vd0 + i * 4;
      Vt[d + 0][vkey] = (__bf16)vv[i].x;
      Vt[d + 1][vkey] = (__bf16)vv[i].y;
      Vt[d + 2][vkey] = (__bf16)vv[i].z;
      Vt[d + 3][vkey] = (__bf16)vv[i].w;
    }
    __syncthreads();
    // ---- S = Q K^T : per wave 32q x 64keys ----
    f32x4 Sa[2][4];
#pragma unroll
    for (int rt = 0; rt < 2; ++rt)
#pragma unroll
      for (int nt = 0; nt < 4; ++nt) Sa[rt][nt] = f32x4{0.f, 0.f, 0.f, 0.f};
#pragma unroll
    for (int nt = 0; nt < 4; ++nt) {
      bf16x8 kf[4];
#pragma unroll
      for (int kc = 0; kc < 4; ++kc)
        kf[kc] = *(bf16x8*)&Kb[nt * 16 + c][kc * 32 + g * 8];
#pragma unroll
      for (int kc = 0; kc < 4; ++kc) {
        Sa[0][nt] = __builtin_amdgcn_mfma_f32_16x16x32_bf16(qf[0][kc], kf[kc], Sa[0][nt], 0, 0, 0);
        Sa[1][nt] = __builtin_amdgcn_mfma_f32_16x16x32_bf16(qf[1][kc], kf[kc], Sa[1][nt], 0, 0, 0);
      }
    }
    // ---- online softmax (rows spread over 16 lanes of c-dim) ----
    float fs_[2][4];
#pragma unroll
    for (int rt = 0; rt < 2; ++rt) {
#pragma unroll
      for (int r = 0; r < 4; ++r) {
        float mx = fmaxf(fmaxf(Sa[rt][0][r], Sa[rt][1][r]),
                         fmaxf(Sa[rt][2][r], Sa[rt][3][r]));
#pragma unroll
        for (int off = 1; off < 16; off <<= 1) mx = fmaxf(mx, __shfl_xor(mx, off));
        float mn = fmaxf(m_[rt][r], mx);
        float fs = __expf(m_[rt][r] - mn);
        m_[rt][r] = mn;
        float ps = 0.f;
        const int prow = wq + rt * 16 + 4 * g + r;
#pragma unroll
        for (int nt = 0; nt < 4; ++nt) {
          float p = __expf(Sa[rt][nt][r] - mn);
          Pl[prow][nt * 16 + c] = (__bf16)p;
          ps += p;
        }
#pragma unroll
        for (int off = 1; off < 16; off <<= 1) ps += __shfl_xor(ps, off);
        l_[rt][r] = l_[rt][r] * fs + ps;
        fs_[rt][r] = fs;
      }
    }
    // ---- rescale O ----
#pragma unroll
    for (int rt = 0; rt < 2; ++rt)
#pragma unroll
      for (int dt = 0; dt < 8; ++dt)
#pragma unroll
        for (int r = 0; r < 4; ++r) Oa[rt][dt][r] *= fs_[rt][r];
    // ---- O += P V ----
#pragma unroll
    for (int k2 = 0; k2 < 2; ++k2) {
      bf16x8 pf0 = *(bf16x8*)&Pl[wq + c][k2 * 32 + g * 8];
      bf16x8 pf1 = *(bf16x8*)&Pl[wq + 16 + c][k2 * 32 + g * 8];
#pragma unroll
      for (int dt = 0; dt < 8; ++dt) {
        bf16x8 vf = *(bf16x8*)&Vt[dt * 16 + c][k2 * 32 + g * 8];
        Oa[0][dt] = __builtin_amdgcn_mfma_f32_16x16x32_bf16(pf0, vf, Oa[0][dt], 0, 0, 0);
        Oa[1][dt] = __builtin_amdgcn_mfma_f32_16x16x32_bf16(pf1, vf, Oa[1][dt], 0, 0, 0);
      }
    }
  }
  // ---- epilogue: divide by l, write in place over Q ----
#pragma unroll
  for (int rt = 0; rt < 2; ++rt) {
#pragma unroll
    for (int r = 0; r < 4; ++r) {
      float inv = 1.0f / l_[rt][r];
      float* orow = Qg + (size_t)(q0 + wq + rt * 16 + 4 * g + r) * rstr;
#pragma unroll
      for (int dt = 0; dt < 8; ++dt)
        orow[dt * 16 + c] = Oa[rt][dt][r] * inv;
    }
  }
}

// ---------------------------------------------------------------------------
extern "C" void kernel_launch(void* const* d_in, const int* in_sizes, int n_in,
                              void* d_out, int out_size, void* d_ws, size_t ws_size,
                              hipStream_t stream) {
  const float* x    = (const float*)d_in[0];
  const float* ln1w = (const float*)d_in[1];
  const float* ln1b = (const float*)d_in[2];
  const float* Wqkv = (const float*)d_in[3];
  const float* bqkv = (const float*)d_in[4];
  const float* qlnw = (const float*)d_in[5];
  const float* klnw = (const float*)d_in[6];
  const float* Wo   = (const float*)d_in[7];
  const float* bo   = (const float*)d_in[8];
  float* out = (float*)d_out;
  float* ws  = (float*)d_ws;

  const size_t qkv_f  = (size_t)NT_ * 3 * HD;
  const size_t need_f = qkv_f + 2 * NT_ + 2 * SEQ_ * 64;
  const size_t need_bytes = need_f * 4;                 // ~193.1 MiB
  if (ws_size < need_bytes) {
    ws_diag_kernel<<<1, 1, 0, stream>>>(out, (float)(ws_size >> 20));
    return;
  }
  float* qkv  = ws;
  float* muv  = qkv + qkv_f;
  float* rsv  = muv + NT_;
  float* ctab = rsv + NT_;
  float* stab = ctab + (size_t)SEQ_ * 64;

  rope_table_kernel<<<(SEQ_ * 64 + 255) / 256, 256, 0, stream>>>(ctab, stab);
  ln_stats_kernel<<<NT_, 256, 0, stream>>>(x, muv, rsv);
  gemm_f32_kernel<true><<<dim3(3 * HD / 128, NT_ / 128), 256, 0, stream>>>(
      x, HD, muv, rsv, ln1w, ln1b, Wqkv, bqkv, qkv, NT_, 3 * HD, HD);
  qkln_rope_kernel<<<NT_, 256, 0, stream>>>(qkv, qlnw, klnw, ctab, stab);
  attn_mfma_kernel<<<dim3(SEQ_ / 128, B_ * NH_), 256, 0, stream>>>(qkv);
  gemm_f32_kernel<false><<<dim3(HD / 128, NT_ / 128), 256, 0, stream>>>(
      qkv, 3 * HD, nullptr, nullptr, nullptr, nullptr, Wo, bo, out,
      NT_, HD, HD);
}

// Round 4
// 1313.503 us; speedup vs baseline: 4.7728x; 2.6715x over previous
//
#include <hip/hip_runtime.h>
#include <math.h>

#define HD   2048
#define NH_  16
#define DH_  128
#define SEQ_ 2048
#define B_   4
#define NT_  (B_*SEQ_)
#define EPS_ 1e-5f

typedef __attribute__((ext_vector_type(8))) __bf16 bf16x8;
typedef __attribute__((ext_vector_type(4))) __bf16 bf16x4;
typedef __attribute__((ext_vector_type(4))) float f32x4;

// ---------------- block-wide sum over 256 threads (4 waves) ----------------
__device__ __forceinline__ float block_sum256(float v, float* red) {
#pragma unroll
  for (int o = 32; o > 0; o >>= 1) v += __shfl_down(v, o);
  int lane = threadIdx.x & 63, wid = threadIdx.x >> 6;
  __syncthreads();
  if (lane == 0) red[wid] = v;
  __syncthreads();
  return red[0] + red[1] + red[2] + red[3];
}

// ---------------- workspace diagnostic (ws too small) ----------------------
__global__ void ws_diag_kernel(float* out, float v) { out[0] = v; }

// ---------------- RoPE cos/sin table (fp64 for accuracy) -------------------
__global__ void rope_table_kernel(float* __restrict__ ct, float* __restrict__ st) {
  int i = blockIdx.x * 256 + threadIdx.x;
  if (i >= SEQ_ * 64) return;
  int l = i >> 6, d = i & 63;
  double invf = exp2(-(double)d * (13.287712379549449 / 64.0));
  double ang = (double)l * invf;
  ct[i] = (float)cos(ang);
  st[i] = (float)sin(ang);
}

// ---------------- LN1 row stats: mu, rsqrt(var+eps) ------------------------
__global__ __launch_bounds__(256) void ln_stats_kernel(const float* __restrict__ x,
    float* __restrict__ mu_out, float* __restrict__ rs_out) {
  __shared__ float red[4];
  int t = threadIdx.x;
  const float4* xr = (const float4*)(x + (size_t)blockIdx.x * HD);
  float4 a = xr[t], b = xr[t + 256];
  float s = a.x + a.y + a.z + a.w + b.x + b.y + b.z + b.w;
  s = block_sum256(s, red);
  float mu = s * (1.0f / HD);
  float dx[8] = {a.x - mu, a.y - mu, a.z - mu, a.w - mu,
                 b.x - mu, b.y - mu, b.z - mu, b.w - mu};
  float ss = 0.f;
#pragma unroll
  for (int i = 0; i < 8; ++i) ss += dx[i] * dx[i];
  ss = block_sum256(ss, red);
  if (t == 0) {
    mu_out[blockIdx.x] = mu;
    rs_out[blockIdx.x] = rsqrtf(ss * (1.0f / HD) + EPS_);
  }
}

// ---------------- W transpose + hi/lo bf16 split: W[K][N] -> Wt[N][K] ------
__global__ __launch_bounds__(256) void wsplit_kernel(const float* __restrict__ W,
    int K, int N, __bf16* __restrict__ Wh, __bf16* __restrict__ Wl) {
  __shared__ float ts[64][69];          // stride 69: gcd(69%32=5,32)=1 -> conflict-free
  int k0 = blockIdx.x << 6, n0 = blockIdx.y << 6;
  int t = threadIdx.x;
#pragma unroll
  for (int i = 0; i < 16; ++i) {
    int lin = t + i * 256;
    int k = lin >> 6, n = lin & 63;
    ts[k][n] = W[(size_t)(k0 + k) * N + n0 + n];
  }
  __syncthreads();
#pragma unroll
  for (int i = 0; i < 16; ++i) {
    int lin = t + i * 256;
    int n = lin >> 6, k = lin & 63;
    float v = ts[k][n];
    __bf16 h = (__bf16)v;
    float lo = v - (float)h;
    size_t o = (size_t)(n0 + n) * K + k0 + k;
    Wh[o] = h;
    Wl[o] = (__bf16)lo;
  }
}

// ---------------- RoPE application helper (4 consecutive dims) -------------
__device__ __forceinline__ float4 rope4(const float* buf, int g, int pos,
                                        const float* __restrict__ ct,
                                        const float* __restrict__ st) {
  int d = g & 127;
  float4 o;
  if (d < 64) {
    float4 cc  = *(const float4*)&ct[pos * 64 + d];
    float4 sn = *(const float4*)&st[pos * 64 + d];
    o.x = buf[g+0]*cc.x - buf[g+64]*sn.x;
    o.y = buf[g+1]*cc.y - buf[g+65]*sn.y;
    o.z = buf[g+2]*cc.z - buf[g+66]*sn.z;
    o.w = buf[g+3]*cc.w - buf[g+67]*sn.w;
  } else {
    int d2 = d - 64;
    float4 cc  = *(const float4*)&ct[pos * 64 + d2];
    float4 sn = *(const float4*)&st[pos * 64 + d2];
    o.x = buf[g+0]*cc.x + buf[g-64]*sn.x;
    o.y = buf[g+1]*cc.y + buf[g-63]*sn.y;
    o.z = buf[g+2]*cc.z + buf[g-62]*sn.z;
    o.w = buf[g+3]*cc.w + buf[g-61]*sn.w;
  }
  return o;
}

// ---------------- fused Q/K layernorm (no bias) + RoPE, in place -----------
__global__ __launch_bounds__(256) void qkln_rope_kernel(float* __restrict__ qkv,
    const float* __restrict__ qw, const float* __restrict__ kw,
    const float* __restrict__ ct, const float* __restrict__ st) {
  __shared__ float red[4];
  __shared__ float buf[HD];
  int t = threadIdx.x;
  int tok = blockIdx.x;
  int pos = tok & (SEQ_ - 1);
  for (int part = 0; part < 2; ++part) {
    float* base = qkv + (size_t)tok * (3 * HD) + (size_t)part * HD;
    const float* w = part ? kw : qw;
    float4 a = ((const float4*)base)[t];
    float4 b = ((const float4*)base)[t + 256];
    float s = a.x + a.y + a.z + a.w + b.x + b.y + b.z + b.w;
    s = block_sum256(s, red);
    float mu = s * (1.0f / HD);
    float dx[8] = {a.x - mu, a.y - mu, a.z - mu, a.w - mu,
                   b.x - mu, b.y - mu, b.z - mu, b.w - mu};
    float ss = 0.f;
#pragma unroll
    for (int i = 0; i < 8; ++i) ss += dx[i] * dx[i];
    ss = block_sum256(ss, red);
    float rs = rsqrtf(ss * (1.0f / HD) + EPS_);
    float4 w0 = ((const float4*)w)[t], w1 = ((const float4*)w)[t + 256];
    int i0 = t * 4, i1 = 1024 + t * 4;
    buf[i0+0] = dx[0]*rs*w0.x; buf[i0+1] = dx[1]*rs*w0.y;
    buf[i0+2] = dx[2]*rs*w0.z; buf[i0+3] = dx[3]*rs*w0.w;
    buf[i1+0] = dx[4]*rs*w1.x; buf[i1+1] = dx[5]*rs*w1.y;
    buf[i1+2] = dx[6]*rs*w1.z; buf[i1+3] = dx[7]*rs*w1.w;
    __syncthreads();
    float4 o0 = rope4(buf, i0, pos, ct, st);
    float4 o1 = rope4(buf, i1, pos, ct, st);
    ((float4*)base)[t] = o0;
    ((float4*)base)[t + 256] = o1;
    __syncthreads();
  }
}

// ---------------- split-bf16 MFMA GEMM: C = lnA[MxK] * W[KxN] + bias -------
// W pre-split+transposed: Wh/Wl are [N][K] bf16. A split on the fly (fp32
// loads, LN fuse optional). 3-term Markidis: Ah*Wh + Ah*Wl + Al*Wh.
// BM=BN=128, BK=32, 4 waves 2x2, wave tile 64x64 = 4x4 mfma_16x16x32 frags.
template<bool FUSE>
__global__ __launch_bounds__(256, 2) void gemm_split_kernel(
    const float* __restrict__ A, int lda,
    const float* __restrict__ mu, const float* __restrict__ rs,
    const float* __restrict__ lnw, const float* __restrict__ lnb,
    const __bf16* __restrict__ Wh, const __bf16* __restrict__ Wl,
    const float* __restrict__ bias,
    float* __restrict__ C, int M, int N, int K) {
  __shared__ __bf16 Ah[128][40], Al[128][40];   // stride 80B = 16B-mult (b128 ok)
  __shared__ __bf16 Bh[128][40], Bl[128][40];
  const int t = threadIdx.x;
  const int row0 = blockIdx.y << 7, col0 = blockIdx.x << 7;
  const int lane = t & 63, wave = t >> 6;
  const int wm = (wave & 1) << 6, wn = (wave >> 1) << 6;
  const int c = lane & 15, g = lane >> 4;
  // staging indices
  const int am = t >> 3, ak = (t & 7) << 2;     // A: 32 rows/iter x 8 k-chunks(4 fp32)
  const int bn = t >> 2, bk = (t & 3) << 3;     // W: 64 rows/iter x 4 k-chunks(8 bf16)

  float mu_[4], rs_[4];
  if (FUSE) {
#pragma unroll
    for (int it = 0; it < 4; ++it) {
      mu_[it] = mu[row0 + am + it * 32];
      rs_[it] = rs[row0 + am + it * 32];
    }
  }
  float bias_[4];
#pragma unroll
  for (int nt = 0; nt < 4; ++nt) bias_[nt] = bias[col0 + wn + nt * 16 + c];

  f32x4 acc[4][4];
#pragma unroll
  for (int mt = 0; mt < 4; ++mt)
#pragma unroll
    for (int nt = 0; nt < 4; ++nt) acc[mt][nt] = f32x4{0.f, 0.f, 0.f, 0.f};

  for (int k0 = 0; k0 < K; k0 += 32) {
    // ---- load to registers ----
    float4 av[4];
#pragma unroll
    for (int it = 0; it < 4; ++it)
      av[it] = *(const float4*)(A + (size_t)(row0 + am + it * 32) * lda + k0 + ak);
    bf16x8 wh[2], wl[2];
#pragma unroll
    for (int jt = 0; jt < 2; ++jt) {
      wh[jt] = *(const bf16x8*)(Wh + (size_t)(col0 + bn + jt * 64) * K + k0 + bk);
      wl[jt] = *(const bf16x8*)(Wl + (size_t)(col0 + bn + jt * 64) * K + k0 + bk);
    }
    float4 w4, b4;
    if (FUSE) {
      w4 = *(const float4*)(lnw + k0 + ak);
      b4 = *(const float4*)(lnb + k0 + ak);
    }
    __syncthreads();   // previous iteration's LDS reads complete
    // ---- convert + stage ----
#pragma unroll
    for (int it = 0; it < 4; ++it) {
      float4 v = av[it];
      if (FUSE) {
        v.x = (v.x - mu_[it]) * rs_[it] * w4.x + b4.x;
        v.y = (v.y - mu_[it]) * rs_[it] * w4.y + b4.y;
        v.z = (v.z - mu_[it]) * rs_[it] * w4.z + b4.z;
        v.w = (v.w - mu_[it]) * rs_[it] * w4.w + b4.w;
      }
      bf16x4 hv, lv;
      hv[0] = (__bf16)v.x; hv[1] = (__bf16)v.y;
      hv[2] = (__bf16)v.z; hv[3] = (__bf16)v.w;
      lv[0] = (__bf16)(v.x - (float)hv[0]); lv[1] = (__bf16)(v.y - (float)hv[1]);
      lv[2] = (__bf16)(v.z - (float)hv[2]); lv[3] = (__bf16)(v.w - (float)hv[3]);
      *(bf16x4*)&Ah[am + it * 32][ak] = hv;
      *(bf16x4*)&Al[am + it * 32][ak] = lv;
    }
#pragma unroll
    for (int jt = 0; jt < 2; ++jt) {
      *(bf16x8*)&Bh[bn + jt * 64][bk] = wh[jt];
      *(bf16x8*)&Bl[bn + jt * 64][bk] = wl[jt];
    }
    __syncthreads();
    // ---- fragments + 48 MFMA ----
    bf16x8 afh[4], afl[4];
#pragma unroll
    for (int mt = 0; mt < 4; ++mt) {
      afh[mt] = *(bf16x8*)&Ah[wm + mt * 16 + c][g * 8];
      afl[mt] = *(bf16x8*)&Al[wm + mt * 16 + c][g * 8];
    }
#pragma unroll
    for (int nt = 0; nt < 4; ++nt) {
      bf16x8 bhv = *(bf16x8*)&Bh[wn + nt * 16 + c][g * 8];
      bf16x8 blv = *(bf16x8*)&Bl[wn + nt * 16 + c][g * 8];
#pragma unroll
      for (int mt = 0; mt < 4; ++mt) {
        acc[mt][nt] = __builtin_amdgcn_mfma_f32_16x16x32_bf16(afh[mt], bhv, acc[mt][nt], 0, 0, 0);
        acc[mt][nt] = __builtin_amdgcn_mfma_f32_16x16x32_bf16(afl[mt], bhv, acc[mt][nt], 0, 0, 0);
        acc[mt][nt] = __builtin_amdgcn_mfma_f32_16x16x32_bf16(afh[mt], blv, acc[mt][nt], 0, 0, 0);
      }
    }
  }
  // ---- epilogue: D-frag row = g*4+r, col = c ----
#pragma unroll
  for (int mt = 0; mt < 4; ++mt) {
#pragma unroll
    for (int r = 0; r < 4; ++r) {
      float* Cr = C + (size_t)(row0 + wm + mt * 16 + g * 4 + r) * N + col0 + wn;
#pragma unroll
      for (int nt = 0; nt < 4; ++nt)
        Cr[nt * 16 + c] = acc[mt][nt][r] + bias_[nt];
    }
  }
}

// ---------------- fp32 tiled GEMM (fallback when ws is small) --------------
template<bool FUSE>
__global__ __launch_bounds__(256) void gemm_f32_kernel(
    const float* __restrict__ A, int lda,
    const float* __restrict__ mu, const float* __restrict__ rs,
    const float* __restrict__ lnw, const float* __restrict__ lnb,
    const float* __restrict__ W, const float* __restrict__ bias,
    float* __restrict__ C, int M, int N, int K) {
  __shared__ float As[16][132];
  __shared__ float Bs[16][132];
  int row0 = blockIdx.y << 7, col0 = blockIdx.x << 7;
  int t = threadIdx.x, tx = t & 15, ty = t >> 4;
  int arow = t >> 2, akc = (t & 3) << 2;
  int brow = t >> 5, bc = (t & 31) << 2;
  const float* Ap0 = A + (size_t)(row0 + arow) * lda + akc;
  const float* Ap1 = A + (size_t)(row0 + arow + 64) * lda + akc;
  const float* Wp0 = W + (size_t)brow * N + col0 + bc;
  const float* Wp1 = W + (size_t)(brow + 8) * N + col0 + bc;
  float mu0 = 0.f, rs0 = 1.f, mu1 = 0.f, rs1 = 1.f;
  if (FUSE) {
    mu0 = mu[row0 + arow];      rs0 = rs[row0 + arow];
    mu1 = mu[row0 + arow + 64]; rs1 = rs[row0 + arow + 64];
  }
  float acc[8][8] = {};
  for (int k0 = 0; k0 < K; k0 += 16) {
    float4 a0 = *(const float4*)(Ap0 + k0);
    float4 a1 = *(const float4*)(Ap1 + k0);
    float4 b0 = *(const float4*)(Wp0 + (size_t)k0 * N);
    float4 b1 = *(const float4*)(Wp1 + (size_t)k0 * N);
    if (FUSE) {
      float4 w4 = *(const float4*)(lnw + k0 + akc);
      float4 b4 = *(const float4*)(lnb + k0 + akc);
      a0.x = (a0.x - mu0) * rs0 * w4.x + b4.x;
      a0.y = (a0.y - mu0) * rs0 * w4.y + b4.y;
      a0.z = (a0.z - mu0) * rs0 * w4.z + b4.z;
      a0.w = (a0.w - mu0) * rs0 * w4.w + b4.w;
      a1.x = (a1.x - mu1) * rs1 * w4.x + b4.x;
      a1.y = (a1.y - mu1) * rs1 * w4.y + b4.y;
      a1.z = (a1.z - mu1) * rs1 * w4.z + b4.z;
      a1.w = (a1.w - mu1) * rs1 * w4.w + b4.w;
    }
    __syncthreads();
    As[akc+0][arow] = a0.x; As[akc+1][arow] = a0.y;
    As[akc+2][arow] = a0.z; As[akc+3][arow] = a0.w;
    As[akc+0][arow+64] = a1.x; As[akc+1][arow+64] = a1.y;
    As[akc+2][arow+64] = a1.z; As[akc+3][arow+64] = a1.w;
    *(float4*)&Bs[brow][bc]   = b0;
    *(float4*)&Bs[brow+8][bc] = b1;
    __syncthreads();
#pragma unroll
    for (int k = 0; k < 16; ++k) {
      float av[8], bv[8];
      *(float4*)&av[0] = *(const float4*)&As[k][ty << 2];
      *(float4*)&av[4] = *(const float4*)&As[k][64 + (ty << 2)];
      *(float4*)&bv[0] = *(const float4*)&Bs[k][tx << 2];
      *(float4*)&bv[4] = *(const float4*)&Bs[k][64 + (tx << 2)];
#pragma unroll
      for (int i = 0; i < 8; ++i)
#pragma unroll
        for (int j = 0; j < 8; ++j)
          acc[i][j] = fmaf(av[i], bv[j], acc[i][j]);
    }
  }
#pragma unroll
  for (int i = 0; i < 8; ++i) {
    int r = row0 + ((i < 4) ? (ty * 4 + i) : (64 + ty * 4 + i - 4));
    float* Cr = C + (size_t)r * N + col0;
    int c0 = tx * 4, c1 = 64 + tx * 4;
    float4 o;
    o.x = acc[i][0] + bias[col0+c0+0]; o.y = acc[i][1] + bias[col0+c0+1];
    o.z = acc[i][2] + bias[col0+c0+2]; o.w = acc[i][3] + bias[col0+c0+3];
    *(float4*)&Cr[c0] = o;
    o.x = acc[i][4] + bias[col0+c1+0]; o.y = acc[i][5] + bias[col0+c1+1];
    o.z = acc[i][6] + bias[col0+c1+2]; o.w = acc[i][7] + bias[col0+c1+3];
    *(float4*)&Cr[c1] = o;
  }
}

// ---------------- flash attention, bf16 MFMA, 128 q-rows per block ---------
__global__ __launch_bounds__(256, 2) void attn_mfma_kernel(float* __restrict__ qkv) {
  __shared__ __bf16 Kb[64][136];
  __shared__ __bf16 Vt[128][72];
  __shared__ __bf16 Pl[128][72];
  const int bh = blockIdx.y, b = bh >> 4, h = bh & 15;
  const int q0 = blockIdx.x << 7;
  const int t = threadIdx.x;
  const int lane = t & 63, wave = t >> 6, g = lane >> 4, c = lane & 15;
  const int wq = wave * 32;
  const size_t rstr = 3 * HD;
  float* Qg = qkv + (size_t)b * SEQ_ * rstr + (size_t)h * DH_;
  const float* Kg = Qg + HD;
  const float* Vg = Qg + 2 * HD;
  const float scale = 0.08838834764831845f;  // 1/sqrt(128)

  bf16x8 qf[2][4];
#pragma unroll
  for (int rt = 0; rt < 2; ++rt) {
    const float* qr = Qg + (size_t)(q0 + wq + rt * 16 + c) * rstr;
#pragma unroll
    for (int kc = 0; kc < 4; ++kc) {
      const int d0 = kc * 32 + g * 8;
      float4 x0 = *(const float4*)(qr + d0);
      float4 x1 = *(const float4*)(qr + d0 + 4);
      bf16x8 f;
      f[0] = (__bf16)(x0.x * scale); f[1] = (__bf16)(x0.y * scale);
      f[2] = (__bf16)(x0.z * scale); f[3] = (__bf16)(x0.w * scale);
      f[4] = (__bf16)(x1.x * scale); f[5] = (__bf16)(x1.y * scale);
      f[6] = (__bf16)(x1.z * scale); f[7] = (__bf16)(x1.w * scale);
      qf[rt][kc] = f;
    }
  }

  f32x4 Oa[2][8];
#pragma unroll
  for (int rt = 0; rt < 2; ++rt)
#pragma unroll
    for (int dt = 0; dt < 8; ++dt) Oa[rt][dt] = f32x4{0.f, 0.f, 0.f, 0.f};
  float m_[2][4], l_[2][4];
#pragma unroll
  for (int rt = 0; rt < 2; ++rt)
#pragma unroll
    for (int r = 0; r < 4; ++r) { m_[rt][r] = -1e30f; l_[rt][r] = 0.f; }

  const int kkey = t >> 5;
  const int kd   = (t & 31) * 4;
  const int vkey = t & 63;
  const int vd0  = (t >> 6) * 32;

  for (int kt = 0; kt < SEQ_; kt += 64) {
    float4 kv[8], vv[8];
#pragma unroll
    for (int i = 0; i < 8; ++i)
      kv[i] = *(const float4*)(Kg + (size_t)(kt + kkey + i * 8) * rstr + kd);
#pragma unroll
    for (int i = 0; i < 8; ++i)
      vv[i] = *(const float4*)(Vg + (size_t)(kt + vkey) * rstr + vd0 + i * 4);
    __syncthreads();
#pragma unroll
    for (int i = 0; i < 8; ++i) {
      bf16x4 kk;
      kk[0] = (__bf16)kv[i].x; kk[1] = (__bf16)kv[i].y;
      kk[2] = (__bf16)kv[i].z; kk[3] = (__bf16)kv[i].w;
      *(bf16x4*)&Kb[kkey + i * 8][kd] = kk;
      const int d = vd0 + i * 4;
      Vt[d + 0][vkey] = (__bf16)vv[i].x;
      Vt[d + 1][vkey] = (__bf16)vv[i].y;
      Vt[d + 2][vkey] = (__bf16)vv[i].z;
      Vt[d + 3][vkey] = (__bf16)vv[i].w;
    }
    __syncthreads();
    f32x4 Sa[2][4];
#pragma unroll
    for (int rt = 0; rt < 2; ++rt)
#pragma unroll
      for (int nt = 0; nt < 4; ++nt) Sa[rt][nt] = f32x4{0.f, 0.f, 0.f, 0.f};
#pragma unroll
    for (int nt = 0; nt < 4; ++nt) {
      bf16x8 kf[4];
#pragma unroll
      for (int kc = 0; kc < 4; ++kc)
        kf[kc] = *(bf16x8*)&Kb[nt * 16 + c][kc * 32 + g * 8];
#pragma unroll
      for (int kc = 0; kc < 4; ++kc) {
        Sa[0][nt] = __builtin_amdgcn_mfma_f32_16x16x32_bf16(qf[0][kc], kf[kc], Sa[0][nt], 0, 0, 0);
        Sa[1][nt] = __builtin_amdgcn_mfma_f32_16x16x32_bf16(qf[1][kc], kf[kc], Sa[1][nt], 0, 0, 0);
      }
    }
    float fs_[2][4];
#pragma unroll
    for (int rt = 0; rt < 2; ++rt) {
#pragma unroll
      for (int r = 0; r < 4; ++r) {
        float mx = fmaxf(fmaxf(Sa[rt][0][r], Sa[rt][1][r]),
                         fmaxf(Sa[rt][2][r], Sa[rt][3][r]));
#pragma unroll
        for (int off = 1; off < 16; off <<= 1) mx = fmaxf(mx, __shfl_xor(mx, off));
        float mn = fmaxf(m_[rt][r], mx);
        float fs = __expf(m_[rt][r] - mn);
        m_[rt][r] = mn;
        float ps = 0.f;
        const int prow = wq + rt * 16 + 4 * g + r;
#pragma unroll
        for (int nt = 0; nt < 4; ++nt) {
          float p = __expf(Sa[rt][nt][r] - mn);
          Pl[prow][nt * 16 + c] = (__bf16)p;
          ps += p;
        }
#pragma unroll
        for (int off = 1; off < 16; off <<= 1) ps += __shfl_xor(ps, off);
        l_[rt][r] = l_[rt][r] * fs + ps;
        fs_[rt][r] = fs;
      }
    }
#pragma unroll
    for (int rt = 0; rt < 2; ++rt)
#pragma unroll
      for (int dt = 0; dt < 8; ++dt)
#pragma unroll
        for (int r = 0; r < 4; ++r) Oa[rt][dt][r] *= fs_[rt][r];
    __syncthreads();
#pragma unroll
    for (int k2 = 0; k2 < 2; ++k2) {
      bf16x8 pf0 = *(bf16x8*)&Pl[wq + c][k2 * 32 + g * 8];
      bf16x8 pf1 = *(bf16x8*)&Pl[wq + 16 + c][k2 * 32 + g * 8];
#pragma unroll
      for (int dt = 0; dt < 8; ++dt) {
        bf16x8 vf = *(bf16x8*)&Vt[dt * 16 + c][k2 * 32 + g * 8];
        Oa[0][dt] = __builtin_amdgcn_mfma_f32_16x16x32_bf16(pf0, vf, Oa[0][dt], 0, 0, 0);
        Oa[1][dt] = __builtin_amdgcn_mfma_f32_16x16x32_bf16(pf1, vf, Oa[1][dt], 0, 0, 0);
      }
    }
  }
#pragma unroll
  for (int rt = 0; rt < 2; ++rt) {
#pragma unroll
    for (int r = 0; r < 4; ++r) {
      float inv = 1.0f / l_[rt][r];
      float* orow = Qg + (size_t)(q0 + wq + rt * 16 + 4 * g + r) * rstr;
#pragma unroll
      for (int dt = 0; dt < 8; ++dt)
        orow[dt * 16 + c] = Oa[rt][dt][r] * inv;
    }
  }
}

// ---------------------------------------------------------------------------
extern "C" void kernel_launch(void* const* d_in, const int* in_sizes, int n_in,
                              void* d_out, int out_size, void* d_ws, size_t ws_size,
                              hipStream_t stream) {
  const float* x    = (const float*)d_in[0];
  const float* ln1w = (const float*)d_in[1];
  const float* ln1b = (const float*)d_in[2];
  const float* Wqkv = (const float*)d_in[3];
  const float* bqkv = (const float*)d_in[4];
  const float* qlnw = (const float*)d_in[5];
  const float* klnw = (const float*)d_in[6];
  const float* Wo   = (const float*)d_in[7];
  const float* bo   = (const float*)d_in[8];
  float* out = (float*)d_out;
  float* ws  = (float*)d_ws;

  // floats: qkv [NT*3H] | mu [NT] | rs [NT] | cos | sin  (== 193.1 MiB)
  const size_t qkv_f  = (size_t)NT_ * 3 * HD;
  const size_t base_f = qkv_f + 2 * NT_ + 2 * SEQ_ * 64;
  const size_t base_bytes  = base_f * 4;                    // 202,440,704
  const size_t wsplit_bytes = (size_t)3 * HD * HD * 2 * 2;  // 50,331,648 (hi+lo)
  const size_t need_split = base_bytes + wsplit_bytes;      // ~241.1 MiB

  if (ws_size < base_bytes) {
    ws_diag_kernel<<<1, 1, 0, stream>>>(out, (float)(ws_size >> 20));
    return;
  }
  float* qkv  = ws;
  float* muv  = qkv + qkv_f;
  float* rsv  = muv + NT_;
  float* ctab = rsv + NT_;
  float* stab = ctab + (size_t)SEQ_ * 64;

  rope_table_kernel<<<(SEQ_ * 64 + 255) / 256, 256, 0, stream>>>(ctab, stab);
  ln_stats_kernel<<<NT_, 256, 0, stream>>>(x, muv, rsv);

  if (ws_size >= need_split) {
    __bf16* Wth = (__bf16*)(ws + base_f);
    __bf16* Wtl = Wth + (size_t)3 * HD * HD;
    // split Wqkv (transposed), QKV GEMM, then reuse buffers for Wo
    wsplit_kernel<<<dim3(HD / 64, 3 * HD / 64), 256, 0, stream>>>(
        Wqkv, HD, 3 * HD, Wth, Wtl);
    gemm_split_kernel<true><<<dim3(3 * HD / 128, NT_ / 128), 256, 0, stream>>>(
        x, HD, muv, rsv, ln1w, ln1b, Wth, Wtl, bqkv, qkv, NT_, 3 * HD, HD);
    wsplit_kernel<<<dim3(HD / 64, HD / 64), 256, 0, stream>>>(
        Wo, HD, HD, Wth, Wtl);
    qkln_rope_kernel<<<NT_, 256, 0, stream>>>(qkv, qlnw, klnw, ctab, stab);
    attn_mfma_kernel<<<dim3(SEQ_ / 128, B_ * NH_), 256, 0, stream>>>(qkv);
    gemm_split_kernel<false><<<dim3(HD / 128, NT_ / 128), 256, 0, stream>>>(
        qkv, 3 * HD, nullptr, nullptr, nullptr, nullptr, Wth, Wtl, bo, out,
        NT_, HD, HD);
  } else {
    // fallback: proven fp32 path
    gemm_f32_kernel<true><<<dim3(3 * HD / 128, NT_ / 128), 256, 0, stream>>>(
        x, HD, muv, rsv, ln1w, ln1b, Wqkv, bqkv, qkv, NT_, 3 * HD, HD);
    qkln_rope_kernel<<<NT_, 256, 0, stream>>>(qkv, qlnw, klnw, ctab, stab);
    attn_mfma_kernel<<<dim3(SEQ_ / 128, B_ * NH_), 256, 0, stream>>>(qkv);
    gemm_f32_kernel<false><<<dim3(HD / 128, NT_ / 128), 256, 0, stream>>>(
        qkv, 3 * HD, nullptr, nullptr, nullptr, nullptr, Wo, bo, out,
        NT_, HD, HD);
  }
}

// Round 5
// 1065.608 us; speedup vs baseline: 5.8831x; 1.2326x over previous
//
#include <hip/hip_runtime.h>
#include <math.h>

#define HD   2048
#define NH_  16
#define DH_  128
#define SEQ_ 2048
#define B_   4
#define NT_  (B_*SEQ_)
#define EPS_ 1e-5f

typedef __attribute__((ext_vector_type(8))) __bf16 bf16x8;
typedef __attribute__((ext_vector_type(4))) __bf16 bf16x4;
typedef __attribute__((ext_vector_type(4))) float f32x4;

typedef const __attribute__((address_space(1))) void* gcptr_t;
typedef __attribute__((address_space(3))) void* lptr_t;

__device__ __forceinline__ void gload16(const void* g, void* l) {
  __builtin_amdgcn_global_load_lds((gcptr_t)g, (lptr_t)l, 16, 0, 0);
}

// ---------------- block-wide sum over 256 threads (4 waves) ----------------
__device__ __forceinline__ float block_sum256(float v, float* red) {
#pragma unroll
  for (int o = 32; o > 0; o >>= 1) v += __shfl_down(v, o);
  int lane = threadIdx.x & 63, wid = threadIdx.x >> 6;
  __syncthreads();
  if (lane == 0) red[wid] = v;
  __syncthreads();
  return red[0] + red[1] + red[2] + red[3];
}

// ---------------- workspace diagnostic (ws too small) ----------------------
__global__ void ws_diag_kernel(float* out, float v) { out[0] = v; }

// ---------------- RoPE cos/sin table (fp64 for accuracy) -------------------
__global__ void rope_table_kernel(float* __restrict__ ct, float* __restrict__ st) {
  int i = blockIdx.x * 256 + threadIdx.x;
  if (i >= SEQ_ * 64) return;
  int l = i >> 6, d = i & 63;
  double invf = exp2(-(double)d * (13.287712379549449 / 64.0));
  double ang = (double)l * invf;
  ct[i] = (float)cos(ang);
  st[i] = (float)sin(ang);
}

// ---------------- LN1 fused + hi/lo bf16 split: x -> Ah, Al ----------------
__global__ __launch_bounds__(256) void ln1_split_kernel(const float* __restrict__ x,
    const float* __restrict__ w, const float* __restrict__ bias,
    __bf16* __restrict__ Ah, __bf16* __restrict__ Al) {
  __shared__ float red[4];
  int t = threadIdx.x;
  const float4* xr = (const float4*)(x + (size_t)blockIdx.x * HD);
  float4 a = xr[t], b = xr[t + 256];
  float s = a.x + a.y + a.z + a.w + b.x + b.y + b.z + b.w;
  s = block_sum256(s, red);
  float mu = s * (1.0f / HD);
  float dx[8] = {a.x - mu, a.y - mu, a.z - mu, a.w - mu,
                 b.x - mu, b.y - mu, b.z - mu, b.w - mu};
  float ss = 0.f;
#pragma unroll
  for (int i = 0; i < 8; ++i) ss += dx[i] * dx[i];
  ss = block_sum256(ss, red);
  float rs = rsqrtf(ss * (1.0f / HD) + EPS_);
  float4 w0 = ((const float4*)w)[t], w1 = ((const float4*)w)[t + 256];
  float4 b0 = ((const float4*)bias)[t], b1 = ((const float4*)bias)[t + 256];
  float y[8];
  y[0] = dx[0]*rs*w0.x + b0.x; y[1] = dx[1]*rs*w0.y + b0.y;
  y[2] = dx[2]*rs*w0.z + b0.z; y[3] = dx[3]*rs*w0.w + b0.w;
  y[4] = dx[4]*rs*w1.x + b1.x; y[5] = dx[5]*rs*w1.y + b1.y;
  y[6] = dx[6]*rs*w1.z + b1.z; y[7] = dx[7]*rs*w1.w + b1.w;
  bf16x4 h0, h1, l0, l1;
#pragma unroll
  for (int i = 0; i < 4; ++i) {
    h0[i] = (__bf16)y[i];     l0[i] = (__bf16)(y[i] - (float)h0[i]);
    h1[i] = (__bf16)y[i + 4]; l1[i] = (__bf16)(y[i + 4] - (float)h1[i]);
  }
  size_t base = (size_t)blockIdx.x * HD;
  *(bf16x4*)&Ah[base + 4 * t] = h0;
  *(bf16x4*)&Ah[base + 1024 + 4 * t] = h1;
  *(bf16x4*)&Al[base + 4 * t] = l0;
  *(bf16x4*)&Al[base + 1024 + 4 * t] = l1;
}

// ---------------- W transpose + hi/lo bf16 split: W[K][N] -> Wt[N][K] ------
__global__ __launch_bounds__(256) void wsplit_kernel(const float* __restrict__ W,
    int K, int N, __bf16* __restrict__ Wh, __bf16* __restrict__ Wl) {
  __shared__ float ts[64][69];
  int k0 = blockIdx.x << 6, n0 = blockIdx.y << 6;
  int t = threadIdx.x;
#pragma unroll
  for (int i = 0; i < 16; ++i) {
    int lin = t + i * 256;
    int k = lin >> 6, n = lin & 63;
    ts[k][n] = W[(size_t)(k0 + k) * N + n0 + n];
  }
  __syncthreads();
#pragma unroll
  for (int i = 0; i < 16; ++i) {
    int lin = t + i * 256;
    int n = lin >> 6, k = lin & 63;
    float v = ts[k][n];
    __bf16 h = (__bf16)v;
    float lo = v - (float)h;
    size_t o = (size_t)(n0 + n) * K + k0 + k;
    Wh[o] = h;
    Wl[o] = (__bf16)lo;
  }
}

// ---------------- fused Q/K layernorm (no bias) + RoPE, bf16 in place ------
__global__ __launch_bounds__(256) void qkln_rope_kernel(__bf16* __restrict__ qkv,
    const float* __restrict__ qw, const float* __restrict__ kw,
    const float* __restrict__ ct, const float* __restrict__ st) {
  __shared__ float red[4];
  __shared__ float buf[HD];
  int t = threadIdx.x;
  int tok = blockIdx.x;
  int pos = tok & (SEQ_ - 1);
  for (int part = 0; part < 2; ++part) {
    __bf16* base = qkv + (size_t)tok * (3 * HD) + (size_t)part * HD;
    const float* w = part ? kw : qw;
    bf16x8 v8 = *(const bf16x8*)(base + 8 * t);
    float x[8];
#pragma unroll
    for (int i = 0; i < 8; ++i) x[i] = (float)v8[i];
    float s = 0.f;
#pragma unroll
    for (int i = 0; i < 8; ++i) s += x[i];
    s = block_sum256(s, red);
    float mu = s * (1.0f / HD);
    float ss = 0.f;
#pragma unroll
    for (int i = 0; i < 8; ++i) { x[i] -= mu; ss += x[i] * x[i]; }
    ss = block_sum256(ss, red);
    float rs = rsqrtf(ss * (1.0f / HD) + EPS_);
    float4 w0 = *(const float4*)&w[8 * t];
    float4 w1 = *(const float4*)&w[8 * t + 4];
    float y[8];
    y[0] = x[0]*rs*w0.x; y[1] = x[1]*rs*w0.y; y[2] = x[2]*rs*w0.z; y[3] = x[3]*rs*w0.w;
    y[4] = x[4]*rs*w1.x; y[5] = x[5]*rs*w1.y; y[6] = x[6]*rs*w1.z; y[7] = x[7]*rs*w1.w;
#pragma unroll
    for (int i = 0; i < 8; ++i) buf[8 * t + i] = y[i];
    __syncthreads();
    int d = (8 * t) & 127;
    int dd = (d < 64) ? d : d - 64;
    int pbase = 8 * t + ((d < 64) ? 64 : -64);
    float4 c0 = *(const float4*)&ct[pos * 64 + dd];
    float4 c1 = *(const float4*)&ct[pos * 64 + dd + 4];
    float4 s0 = *(const float4*)&st[pos * 64 + dd];
    float4 s1 = *(const float4*)&st[pos * 64 + dd + 4];
    float cv[8] = {c0.x, c0.y, c0.z, c0.w, c1.x, c1.y, c1.z, c1.w};
    float sv[8] = {s0.x, s0.y, s0.z, s0.w, s1.x, s1.y, s1.z, s1.w};
    bf16x8 o8;
    if (d < 64) {
#pragma unroll
      for (int i = 0; i < 8; ++i) o8[i] = (__bf16)(y[i] * cv[i] - buf[pbase + i] * sv[i]);
    } else {
#pragma unroll
      for (int i = 0; i < 8; ++i) o8[i] = (__bf16)(y[i] * cv[i] + buf[pbase + i] * sv[i]);
    }
    *(bf16x8*)(base + 8 * t) = o8;
    __syncthreads();
  }
}

// ---------------- pure-bf16 3-term split GEMM (gload_lds + XOR swizzle) ----
// A (Ah/Al): [M][K] bf16 row-major; B (Bh/Bl): [N][K] bf16 (W^T).
// C = (Ah+Al)*(Bh+Bl)^T + bias  (3-term Markidis, Al*Bl dropped).
// BM=BN=128, BK=64, 256 thr (4 waves 2x2). LDS linear [4][128][64] bf16;
// swizzle: 16B-chunk ch at row r holds global k-chunk ch^(r&7) (both-sides).
template<bool OUTBF16>
__global__ __launch_bounds__(256, 2) void gemm_bf3_kernel(
    const __bf16* __restrict__ Ah, const __bf16* __restrict__ Al,
    const __bf16* __restrict__ Bh, const __bf16* __restrict__ Bl,
    const float* __restrict__ bias, void* __restrict__ C,
    int M, int N, int K) {
  __shared__ __bf16 lds[4][128][64];
  const int t = threadIdx.x;
  const int lane = t & 63, wave = t >> 6;
  const int c = lane & 15, g = lane >> 4;
  const int wm = (wave & 1) << 6, wn = (wave >> 1) << 6;

  // XCD-aware block swizzle (nwg = 3072 or 1024, both % 8 == 0)
  const int nwg = gridDim.x * gridDim.y;
  int lin = blockIdx.y * gridDim.x + blockIdx.x;
  int swz = (lin & 7) * (nwg >> 3) + (lin >> 3);
  const int col0 = (swz % gridDim.x) << 7;
  const int row0 = (swz / gridDim.x) << 7;

  // staging source offsets (loop-invariant): wave w stages rows [w*32,w*32+32)
  const int srow = (wave << 5) + (lane >> 3);  // + i*8
  const int ch = lane & 7;
  size_t offA[4], offB[4];
#pragma unroll
  for (int i = 0; i < 4; ++i) {
    int rA = srow + i * 8;
    offA[i] = (size_t)(row0 + rA) * (K * 2) + (size_t)((ch ^ (rA & 7)) << 4);
    offB[i] = (size_t)(col0 + rA) * (K * 2) + (size_t)((ch ^ (rA & 7)) << 4);
  }
  const char* pAh = (const char*)Ah;
  const char* pAl = (const char*)Al;
  const char* pBh = (const char*)Bh;
  const char* pBl = (const char*)Bl;

  float bias_[4];
#pragma unroll
  for (int nt = 0; nt < 4; ++nt) bias_[nt] = bias[col0 + wn + nt * 16 + c];

  f32x4 acc[4][4];
#pragma unroll
  for (int mt = 0; mt < 4; ++mt)
#pragma unroll
    for (int nt = 0; nt < 4; ++nt) acc[mt][nt] = f32x4{0.f, 0.f, 0.f, 0.f};

  for (int k0 = 0; k0 < K; k0 += 64) {
    const size_t k2 = (size_t)k0 * 2;
    __syncthreads();   // previous iteration's frag reads complete
#pragma unroll
    for (int i = 0; i < 4; ++i) {
      const int lr = (wave << 5) + (i << 3);
      gload16(pAh + offA[i] + k2, &lds[0][lr][0]);
      gload16(pAl + offA[i] + k2, &lds[1][lr][0]);
      gload16(pBh + offB[i] + k2, &lds[2][lr][0]);
      gload16(pBl + offB[i] + k2, &lds[3][lr][0]);
    }
    __syncthreads();   // drains vmcnt(0): staged data visible
#pragma unroll
    for (int kc = 0; kc < 2; ++kc) {
      bf16x8 ah[4], al[4];
#pragma unroll
      for (int mt = 0; mt < 4; ++mt) {
        const int r = wm + mt * 16 + c;
        const int cb = (((kc << 2) | g) ^ (r & 7)) << 4;
        ah[mt] = *(const bf16x8*)((const char*)&lds[0][0][0] + (r << 7) + cb);
        al[mt] = *(const bf16x8*)((const char*)&lds[1][0][0] + (r << 7) + cb);
      }
#pragma unroll
      for (int nt = 0; nt < 4; ++nt) {
        const int r = wn + nt * 16 + c;
        const int cb = (((kc << 2) | g) ^ (r & 7)) << 4;
        bf16x8 bh = *(const bf16x8*)((const char*)&lds[2][0][0] + (r << 7) + cb);
        bf16x8 bl = *(const bf16x8*)((const char*)&lds[3][0][0] + (r << 7) + cb);
#pragma unroll
        for (int mt = 0; mt < 4; ++mt) {
          acc[mt][nt] = __builtin_amdgcn_mfma_f32_16x16x32_bf16(ah[mt], bh, acc[mt][nt], 0, 0, 0);
          acc[mt][nt] = __builtin_amdgcn_mfma_f32_16x16x32_bf16(al[mt], bh, acc[mt][nt], 0, 0, 0);
          acc[mt][nt] = __builtin_amdgcn_mfma_f32_16x16x32_bf16(ah[mt], bl, acc[mt][nt], 0, 0, 0);
        }
      }
    }
  }
  // epilogue: D-frag row = g*4+r, col = c
#pragma unroll
  for (int mt = 0; mt < 4; ++mt) {
#pragma unroll
    for (int r = 0; r < 4; ++r) {
      const size_t row = (size_t)(row0 + wm + mt * 16 + g * 4 + r);
#pragma unroll
      for (int nt = 0; nt < 4; ++nt) {
        float v = acc[mt][nt][r] + bias_[nt];
        size_t idx = row * N + col0 + wn + nt * 16 + c;
        if (OUTBF16) ((__bf16*)C)[idx] = (__bf16)v;
        else         ((float*)C)[idx] = v;
      }
    }
  }
}

// ---------------- flash attention, bf16 MFMA, 128 q-rows per block ---------
// qkv is bf16. Scale folded into S post-MFMA. O written as hi/lo bf16
// into Oh/Ol (the Ah/Al buffers, free after the QKV GEMM).
__global__ __launch_bounds__(256, 2) void attn_mfma_kernel(
    const __bf16* __restrict__ qkv,
    __bf16* __restrict__ Oh, __bf16* __restrict__ Ol) {
  __shared__ __bf16 Kb[64][136];
  __shared__ __bf16 Vt[128][72];
  __shared__ __bf16 Pl[128][72];
  const int bh = blockIdx.y, b = bh >> 4, h = bh & 15;
  const int q0 = blockIdx.x << 7;
  const int t = threadIdx.x;
  const int lane = t & 63, wave = t >> 6, g = lane >> 4, c = lane & 15;
  const int wq = wave * 32;
  const size_t rstr = 3 * HD;
  const __bf16* Qg = qkv + (size_t)b * SEQ_ * rstr + (size_t)h * DH_;
  const __bf16* Kg = Qg + HD;
  const __bf16* Vg = Qg + 2 * HD;
  const float scale = 0.08838834764831845f;  // 1/sqrt(128)

  bf16x8 qf[2][4];
#pragma unroll
  for (int rt = 0; rt < 2; ++rt) {
    const __bf16* qr = Qg + (size_t)(q0 + wq + rt * 16 + c) * rstr;
#pragma unroll
    for (int kc = 0; kc < 4; ++kc)
      qf[rt][kc] = *(const bf16x8*)(qr + kc * 32 + g * 8);
  }

  f32x4 Oa[2][8];
#pragma unroll
  for (int rt = 0; rt < 2; ++rt)
#pragma unroll
    for (int dt = 0; dt < 8; ++dt) Oa[rt][dt] = f32x4{0.f, 0.f, 0.f, 0.f};
  float m_[2][4], l_[2][4];
#pragma unroll
  for (int rt = 0; rt < 2; ++rt)
#pragma unroll
    for (int r = 0; r < 4; ++r) { m_[rt][r] = -1e30f; l_[rt][r] = 0.f; }

  const int krow = t >> 4;          // 0..15 (+16i)
  const int kcol = (t & 15) * 8;
  const int vkey = t & 63;
  const int vd0  = (t >> 6) * 32;

  for (int kt = 0; kt < SEQ_; kt += 64) {
    bf16x8 kv[4], vv[4];
#pragma unroll
    for (int i = 0; i < 4; ++i)
      kv[i] = *(const bf16x8*)(Kg + (size_t)(kt + krow + i * 16) * rstr + kcol);
#pragma unroll
    for (int i = 0; i < 4; ++i)
      vv[i] = *(const bf16x8*)(Vg + (size_t)(kt + vkey) * rstr + vd0 + i * 8);
    __syncthreads();
#pragma unroll
    for (int i = 0; i < 4; ++i) {
      *(bf16x8*)&Kb[krow + i * 16][kcol] = kv[i];
#pragma unroll
      for (int j = 0; j < 8; ++j) Vt[vd0 + i * 8 + j][vkey] = vv[i][j];
    }
    __syncthreads();
    f32x4 Sa[2][4];
#pragma unroll
    for (int rt = 0; rt < 2; ++rt)
#pragma unroll
      for (int nt = 0; nt < 4; ++nt) Sa[rt][nt] = f32x4{0.f, 0.f, 0.f, 0.f};
#pragma unroll
    for (int nt = 0; nt < 4; ++nt) {
      bf16x8 kf[4];
#pragma unroll
      for (int kc = 0; kc < 4; ++kc)
        kf[kc] = *(bf16x8*)&Kb[nt * 16 + c][kc * 32 + g * 8];
#pragma unroll
      for (int kc = 0; kc < 4; ++kc) {
        Sa[0][nt] = __builtin_amdgcn_mfma_f32_16x16x32_bf16(qf[0][kc], kf[kc], Sa[0][nt], 0, 0, 0);
        Sa[1][nt] = __builtin_amdgcn_mfma_f32_16x16x32_bf16(qf[1][kc], kf[kc], Sa[1][nt], 0, 0, 0);
      }
    }
#pragma unroll
    for (int rt = 0; rt < 2; ++rt)
#pragma unroll
      for (int nt = 0; nt < 4; ++nt)
#pragma unroll
        for (int r = 0; r < 4; ++r) Sa[rt][nt][r] *= scale;
    float fs_[2][4];
#pragma unroll
    for (int rt = 0; rt < 2; ++rt) {
#pragma unroll
      for (int r = 0; r < 4; ++r) {
        float mx = fmaxf(fmaxf(Sa[rt][0][r], Sa[rt][1][r]),
                         fmaxf(Sa[rt][2][r], Sa[rt][3][r]));
#pragma unroll
        for (int off = 1; off < 16; off <<= 1) mx = fmaxf(mx, __shfl_xor(mx, off));
        float mn = fmaxf(m_[rt][r], mx);
        float fs = __expf(m_[rt][r] - mn);
        m_[rt][r] = mn;
        float ps = 0.f;
        const int prow = wq + rt * 16 + 4 * g + r;
#pragma unroll
        for (int nt = 0; nt < 4; ++nt) {
          float p = __expf(Sa[rt][nt][r] - mn);
          Pl[prow][nt * 16 + c] = (__bf16)p;
          ps += p;
        }
#pragma unroll
        for (int off = 1; off < 16; off <<= 1) ps += __shfl_xor(ps, off);
        l_[rt][r] = l_[rt][r] * fs + ps;
        fs_[rt][r] = fs;
      }
    }
#pragma unroll
    for (int rt = 0; rt < 2; ++rt)
#pragma unroll
      for (int dt = 0; dt < 8; ++dt)
#pragma unroll
        for (int r = 0; r < 4; ++r) Oa[rt][dt][r] *= fs_[rt][r];
    __syncthreads();
#pragma unroll
    for (int k2 = 0; k2 < 2; ++k2) {
      bf16x8 pf0 = *(bf16x8*)&Pl[wq + c][k2 * 32 + g * 8];
      bf16x8 pf1 = *(bf16x8*)&Pl[wq + 16 + c][k2 * 32 + g * 8];
#pragma unroll
      for (int dt = 0; dt < 8; ++dt) {
        bf16x8 vf = *(bf16x8*)&Vt[dt * 16 + c][k2 * 32 + g * 8];
        Oa[0][dt] = __builtin_amdgcn_mfma_f32_16x16x32_bf16(pf0, vf, Oa[0][dt], 0, 0, 0);
        Oa[1][dt] = __builtin_amdgcn_mfma_f32_16x16x32_bf16(pf1, vf, Oa[1][dt], 0, 0, 0);
      }
    }
  }
#pragma unroll
  for (int rt = 0; rt < 2; ++rt) {
#pragma unroll
    for (int r = 0; r < 4; ++r) {
      float inv = 1.0f / l_[rt][r];
      size_t obase = (size_t)(b * SEQ_ + q0 + wq + rt * 16 + 4 * g + r) * HD + h * DH_;
#pragma unroll
      for (int dt = 0; dt < 8; ++dt) {
        float v = Oa[rt][dt][r] * inv;
        __bf16 hi = (__bf16)v;
        Oh[obase + dt * 16 + c] = hi;
        Ol[obase + dt * 16 + c] = (__bf16)(v - (float)hi);
      }
    }
  }
}

// ---------------------------------------------------------------------------
extern "C" void kernel_launch(void* const* d_in, const int* in_sizes, int n_in,
                              void* d_out, int out_size, void* d_ws, size_t ws_size,
                              hipStream_t stream) {
  const float* x    = (const float*)d_in[0];
  const float* ln1w = (const float*)d_in[1];
  const float* ln1b = (const float*)d_in[2];
  const float* Wqkv = (const float*)d_in[3];
  const float* bqkv = (const float*)d_in[4];
  const float* qlnw = (const float*)d_in[5];
  const float* klnw = (const float*)d_in[6];
  const float* Wo   = (const float*)d_in[7];
  const float* bo   = (const float*)d_in[8];
  float* out = (float*)d_out;

  // ws layout (bytes): qkv bf16 | Ah | Al | Wth | Wtl | ctab | stab  (~209 MiB)
  const size_t qkv_b = (size_t)NT_ * 3 * HD * 2;      // 100.7 MB
  const size_t a_b   = (size_t)NT_ * HD * 2;          // 33.6 MB each
  const size_t w_b   = (size_t)3 * HD * HD * 2;       // 25.2 MB each
  const size_t t_b   = (size_t)SEQ_ * 64 * 4;         // 0.5 MB each
  const size_t need  = qkv_b + 2 * a_b + 2 * w_b + 2 * t_b;
  if (ws_size < need) {
    ws_diag_kernel<<<1, 1, 0, stream>>>(out, (float)(ws_size >> 20));
    return;
  }
  char* w = (char*)d_ws;
  __bf16* qkvb = (__bf16*)w;              w += qkv_b;
  __bf16* Ah   = (__bf16*)w;              w += a_b;
  __bf16* Al   = (__bf16*)w;              w += a_b;
  __bf16* Wth  = (__bf16*)w;              w += w_b;
  __bf16* Wtl  = (__bf16*)w;              w += w_b;
  float*  ctab = (float*)w;               w += t_b;
  float*  stab = (float*)w;

  rope_table_kernel<<<(SEQ_ * 64 + 255) / 256, 256, 0, stream>>>(ctab, stab);
  ln1_split_kernel<<<NT_, 256, 0, stream>>>(x, ln1w, ln1b, Ah, Al);
  wsplit_kernel<<<dim3(HD / 64, 3 * HD / 64), 256, 0, stream>>>(
      Wqkv, HD, 3 * HD, Wth, Wtl);
  gemm_bf3_kernel<true><<<dim3(3 * HD / 128, NT_ / 128), 256, 0, stream>>>(
      Ah, Al, Wth, Wtl, bqkv, qkvb, NT_, 3 * HD, HD);
  qkln_rope_kernel<<<NT_, 256, 0, stream>>>(qkvb, qlnw, klnw, ctab, stab);
  wsplit_kernel<<<dim3(HD / 64, HD / 64), 256, 0, stream>>>(
      Wo, HD, HD, Wth, Wtl);                       // after QKV GEMM (reuse)
  attn_mfma_kernel<<<dim3(SEQ_ / 128, B_ * NH_), 256, 0, stream>>>(
      qkvb, Ah, Al);                               // O -> Ah/Al (reuse)
  gemm_bf3_kernel<false><<<dim3(HD / 128, NT_ / 128), 256, 0, stream>>>(
      Ah, Al, Wth, Wtl, bo, out, NT_, HD, HD);
}